// Round 5
// baseline (8430.732 us; speedup 1.0000x reference)
//
#include <hip/hip_runtime.h>
#include <math.h>

// Problem constants (match reference)
#define B_   4096
#define N_   50
#define D_   128
#define DV_  8
#define FS_  4
#define SE_  20
#define TPH_ 64
#define NEGV (-1e9f)
#define G_   16          // batch rows per decode block (1 wave per row)
#define NBLK (B_ / G_)   // 256 blocks, 1 per CU

// ---------- fast math helpers (fp32, abs err ~1e-7 — safe for argmax) ----------
__device__ __forceinline__ float frcp_(float x) { return __builtin_amdgcn_rcpf(x); }
__device__ __forceinline__ float ftanh_(float x) {
    float e = __expf(2.f * x);               // inf-safe: x>>0 -> e=inf -> rcp=0 -> 1
    return 1.f - 2.f * frcp_(e + 1.f);
}
__device__ __forceinline__ float fsig_(float x) {
    return frcp_(1.f + __expf(-x));
}
__device__ __forceinline__ float wsum_(float v) {
#pragma unroll
    for (int m = 1; m < 64; m <<= 1) v += __shfl_xor(v, m);
    return v;
}

// ---------- kernel A: e = einsum('de,nbe->bnd', W, cu) + bias  -> [B][N][D] ----------
__global__ __launch_bounds__(256) void proj_kernel(
    const float* __restrict__ W,     // [128][128]
    const float* __restrict__ bias,  // [128]
    const float* __restrict__ cu,    // [N][B][D]
    float* __restrict__ outp)        // [B][N][D] (row r = b*N+n)
{
    __shared__ __align__(16) float scu[20][128];
    __shared__ float sb[128];
    const int tid = threadIdx.x;
    if (tid < 128) sb[tid] = bias[tid];
    const int d  = tid & 127;
    const int rq = tid >> 7;   // 0..1
    const float* wrow = W + d * 128;
    const int r0 = blockIdx.x * 200;
    for (int it = 0; it < 10; ++it) {
        const int rbase = r0 + it * 20;
        __syncthreads();
        for (int i = tid; i < 20 * 128; i += 256) {
            int rr = i >> 7, e = i & 127;
            int r = rbase + rr;
            int b = r / 50, n = r - b * 50;
            scu[rr][e] = cu[((size_t)n * B_ + b) * D_ + e];
        }
        __syncthreads();
        float acc[10];
#pragma unroll
        for (int k = 0; k < 10; ++k) acc[k] = 0.f;
        const int rr0 = rq * 10;
        for (int e = 0; e < 128; e += 4) {
            float4 w4 = *(const float4*)&wrow[e];
#pragma unroll
            for (int k = 0; k < 10; ++k) {
                float4 c4 = *(const float4*)&scu[rr0 + k][e];   // wave-uniform: LDS broadcast
                acc[k] += w4.x * c4.x + w4.y * c4.y + w4.z * c4.z + w4.w * c4.w;
            }
        }
        float bv = sb[d];
#pragma unroll
        for (int k = 0; k < 10; ++k)
            outp[(size_t)(rbase + rr0 + k) * D_ + d] = acc[k] + bv;   // coalesced over d
    }
}

// ---------- kernel T: out[c][r] = in[r][c]  (tiny, run once) ----------
__global__ __launch_bounds__(256) void transpose_kernel(
    const float* __restrict__ in, float* __restrict__ out, int R, int C)
{
    int idx = blockIdx.x * 256 + threadIdx.x;
    if (idx < R * C) {
        int r = idx / C, c = idx - r * C;
        out[c * R + r] = in[idx];     // coalesced read, scattered write; matrix is tiny
    }
}

// ---------- kernel B: persistent 50-step decode, one block = 16 batch rows ----------
// Structure per step: P1 (cross-wave gates GEMM) | barrier | per-wave section
// {P2 LSTM, mask, P3 qg-GEMV, P4 glimpse, P5 qp-GEMV, P6 pointer+epilogue} | barrier.
// Only 2 barriers/step; waves drift independently through the section.
__global__ __launch_bounds__(1024, 4) void decode_kernel(
    const float* __restrict__ dec_in,     // [B][D]
    const float* __restrict__ h0,
    const float* __restrict__ c0,
    const unsigned char* __restrict__ vmask,  // [B][N] bool bytes
    const int* __restrict__ start_idx,    // [B]
    const float* __restrict__ V,          // [B][N][DV]
    const float* __restrict__ cu,         // [N][B][D]
    const float* __restrict__ start_fea,  // [B][FS]
    const float* __restrict__ W_ih,       // [512][128]
    const float* __restrict__ W_hh,       // [512][128]
    const float* __restrict__ b_ih, const float* __restrict__ b_hh,
    const float* __restrict__ gWq, const float* __restrict__ gbq,
    const float* __restrict__ gv,
    const float* __restrict__ pWq, const float* __restrict__ pbq,
    const float* __restrict__ pv,
    const float* __restrict__ step_table, // [51][20]
    const float* __restrict__ tpW1, const float* __restrict__ tpb1,  // [40][64],[64]
    const float* __restrict__ tpW2, const float* __restrict__ tpb2,  // [64],[1]
    const float* __restrict__ e_g, const float* __restrict__ e_p,    // [B][N][D]
    const float* __restrict__ wtI,        // [128][512] = W_ih^T (valid iff use_t)
    const float* __restrict__ wtH,        // [128][512] = W_hh^T
    const float* __restrict__ gqT,        // [128][128] = gWq^T
    const float* __restrict__ pqT,        // [128][128] = pWq^T
    const int use_t,
    float* __restrict__ outp)
{
    __shared__ __align__(16) float sH[G_][D_];
    __shared__ __align__(16) float sC[G_][D_];
    __shared__ __align__(16) float sX[G_][D_];
    __shared__ __align__(16) float sU[G_ * 512];    // gates (e-low half when use_t)
    __shared__ __align__(16) float sP2[G_ * 512];   // gates e-high partials (use_t)
    __shared__ __align__(16) float sQ[G_][D_];      // qg then qp (wave-local)
    __shared__ __align__(16) float sGl[G_][D_];     // glimpse output (wave-local)
    __shared__ float sLg[G_][64];                   // pointer logits staging (wave-local)
    __shared__ float sBias[512];
    __shared__ __align__(16) float sGbq[128];
    __shared__ __align__(16) float sPbq[128];
    __shared__ __align__(16) float sGv[128];
    __shared__ __align__(16) float sPv[128];
    __shared__ float sSF[G_][FS_];

    const int tid  = threadIdx.x;
    const int b0   = blockIdx.x * G_;
    const int g    = tid >> 6;        // wave id == batch row within block
    const int lane = tid & 63;
    const int b    = b0 + g;

    // ---- init ----
    for (int i = tid; i < G_ * D_; i += 1024) {
        int gg = i >> 7, d = i & 127;
        size_t src = (size_t)(b0 + gg) * D_ + d;
        sH[gg][d] = h0[src];
        sC[gg][d] = c0[src];
        sX[gg][d] = dec_in[src];
    }
    if (tid < 512)       sBias[tid]      = b_ih[tid] + b_hh[tid];
    else if (tid < 640)  sGbq[tid - 512] = gbq[tid - 512];
    else if (tid < 768)  sPbq[tid - 640] = pbq[tid - 640];
    else if (tid < 896)  sGv[tid - 768]  = gv[tid - 768];
    else                 sPv[tid - 896]  = pv[tid - 896];
    if (tid < G_ * FS_) {
        int gg = tid >> 2, k = tid & 3;
        sSF[gg][k] = start_fea[(size_t)(b0 + gg) * FS_ + k];
    }
    // per-wave persistent state in registers
    unsigned char mv = (lane < N_) ? vmask[(size_t)b * N_ + lane] : (unsigned char)0;
    unsigned long long mk = __ballot(mv != 0);
    int lastv = start_idx[b];
    int prev  = 0;
    __syncthreads();

    const unsigned long long FULL = (1ull << N_) - 1ull;
    const int nh = lane >> 5;         // row-within-pair for stream phases
    const int dq = lane & 31;         // 4-float chunk within row

    for (int t = 0; t < N_; ++t) {
        // ---- P1: gates = x@W_ih.T + h@W_hh.T + (b_ih+b_hh)  (cross-wave GEMM) ----
        if (use_t) {
            const int j  = tid & 511;
            const int eh = tid >> 9;              // 0/1
            const int ebase = eh * 64;
            const float* wI = wtI + j;            // stride 512 floats per e, coalesced
            const float* wH = wtH + j;
            float acc[16];
#pragma unroll
            for (int q = 0; q < 16; ++q) acc[q] = 0.f;
#pragma unroll 2
            for (int ec = 0; ec < 64; ec += 4) {
                const int e = ebase + ec;
                float wi0 = wI[(size_t)(e + 0) * 512], wi1 = wI[(size_t)(e + 1) * 512];
                float wi2 = wI[(size_t)(e + 2) * 512], wi3 = wI[(size_t)(e + 3) * 512];
                float wh0 = wH[(size_t)(e + 0) * 512], wh1 = wH[(size_t)(e + 1) * 512];
                float wh2 = wH[(size_t)(e + 2) * 512], wh3 = wH[(size_t)(e + 3) * 512];
#pragma unroll
                for (int q = 0; q < 16; ++q) {
                    float4 x4 = *(const float4*)&sX[q][e];   // wave-uniform LDS broadcast
                    float4 h4 = *(const float4*)&sH[q][e];
                    acc[q] += wi0 * x4.x + wi1 * x4.y + wi2 * x4.z + wi3 * x4.w
                            + wh0 * h4.x + wh1 * h4.y + wh2 * h4.z + wh3 * h4.w;
                }
            }
            if (eh == 0) {
                float bb = sBias[j];
#pragma unroll
                for (int q = 0; q < 16; ++q) sU[q * 512 + j] = acc[q] + bb;
            } else {
#pragma unroll
                for (int q = 0; q < 16; ++q) sP2[q * 512 + j] = acc[q];
            }
        } else {
            const int j  = tid & 511;
            const int gh = tid >> 9;
            const int gbase = gh * 8;
            const float* wih = W_ih + (size_t)j * 128;
            const float* whh = W_hh + (size_t)j * 128;
            float acc[8];
#pragma unroll
            for (int q = 0; q < 8; ++q) acc[q] = 0.f;
            for (int e = 0; e < 128; e += 16) {
                float4 wi[4], wh[4];
#pragma unroll
                for (int w = 0; w < 4; ++w) {
                    wi[w] = *(const float4*)&wih[e + 4 * w];
                    wh[w] = *(const float4*)&whh[e + 4 * w];
                }
#pragma unroll
                for (int q = 0; q < 8; ++q) {
                    const float* xr = &sX[gbase + q][e];
                    const float* hr = &sH[gbase + q][e];
#pragma unroll
                    for (int w = 0; w < 4; ++w) {
                        float4 x4 = *(const float4*)&xr[4 * w];
                        float4 h4 = *(const float4*)&hr[4 * w];
                        acc[q] += wi[w].x * x4.x + wi[w].y * x4.y + wi[w].z * x4.z + wi[w].w * x4.w
                                + wh[w].x * h4.x + wh[w].y * h4.y + wh[w].z * h4.z + wh[w].w * h4.w;
                    }
                }
            }
            float bb = sBias[j];
#pragma unroll
            for (int q = 0; q < 8; ++q) sU[(gbase + q) * 512 + j] = acc[q] + bb;
        }
        __syncthreads();

        // ================= per-wave independent section (no barriers) =================
        // ---- P2: LSTM pointwise for own g ----
#pragma unroll
        for (int h = 0; h < 2; ++h) {
            const int d = lane + h * 64;
            float u0 = sU[g * 512 + d],       u1 = sU[g * 512 + 128 + d];
            float u2 = sU[g * 512 + 256 + d], u3 = sU[g * 512 + 384 + d];
            if (use_t) {
                u0 += sP2[g * 512 + d];       u1 += sP2[g * 512 + 128 + d];
                u2 += sP2[g * 512 + 256 + d]; u3 += sP2[g * 512 + 384 + d];
            }
            float ig = fsig_(u0), fg = fsig_(u1), gg2 = ftanh_(u2), og = fsig_(u3);
            float c2 = fg * sC[g][d] + ig * gg2;
            sC[g][d] = c2;
            sH[g][d] = og * ftanh_(c2);
        }
        // ---- P0: mask update (registers, wave-uniform) ----
        if (t > 0) mk |= (1ull << prev);
        if ((mk & FULL) == FULL) mk &= ~(1ull << (N_ - 1));

        // ---- P3: qg = sH[g] @ gWq^T + gbq  -> sQ[g] (per-wave GEMV, coalesced) ----
        if (use_t) {
            const float* wq = gqT + 2 * lane;     // two output columns per lane
            float a0 = 0.f, a1 = 0.f;
#pragma unroll 8
            for (int e = 0; e < 128; e += 4) {
                float4 h4 = *(const float4*)&sH[g][e];          // wave-uniform broadcast
                float2 w0 = *(const float2*)&wq[(size_t)(e + 0) * 128];
                float2 w1 = *(const float2*)&wq[(size_t)(e + 1) * 128];
                float2 w2 = *(const float2*)&wq[(size_t)(e + 2) * 128];
                float2 w3 = *(const float2*)&wq[(size_t)(e + 3) * 128];
                a0 += w0.x * h4.x + w1.x * h4.y + w2.x * h4.z + w3.x * h4.w;
                a1 += w0.y * h4.x + w1.y * h4.y + w2.y * h4.z + w3.y * h4.w;
            }
            sQ[g][2 * lane]     = a0 + sGbq[2 * lane];
            sQ[g][2 * lane + 1] = a1 + sGbq[2 * lane + 1];
        } else {
            const float* w0r = gWq + (size_t)(2 * lane) * 128;
            const float* w1r = w0r + 128;
            float a0 = 0.f, a1 = 0.f;
            for (int e = 0; e < 128; e += 4) {
                float4 h4 = *(const float4*)&sH[g][e];
                float4 wa = *(const float4*)&w0r[e];
                float4 wb = *(const float4*)&w1r[e];
                a0 += wa.x * h4.x + wa.y * h4.y + wa.z * h4.z + wa.w * h4.w;
                a1 += wb.x * h4.x + wb.y * h4.y + wb.z * h4.z + wb.w * h4.w;
            }
            sQ[g][2 * lane]     = a0 + sGbq[2 * lane];
            sQ[g][2 * lane + 1] = a1 + sGbq[2 * lane + 1];
        }

        // ---- P4: glimpse, 2 rows per iter, 1 KB/load-instruction, 5 shfl / 2 rows ----
        {
            float4 qg4 = *(const float4*)&sQ[g][dq * 4];
            float4 gv4 = *(const float4*)&sGv[dq * 4];
            const float* egb = e_g + (size_t)b * (N_ * D_) + nh * D_ + dq * 4;
            float4 p0 = *(const float4*)&egb[0 * 256];
            float4 p1 = *(const float4*)&egb[1 * 256];
            float4 p2 = *(const float4*)&egb[2 * 256];
            float4 p3 = *(const float4*)&egb[3 * 256];
            float l = 0.f;
            float4 acc = {0.f, 0.f, 0.f, 0.f};
#pragma unroll
            for (int blk = 0; blk < 25; ++blk) {
                float4 c = p0; p0 = p1; p1 = p2; p2 = p3;
                if (blk + 4 < 25) p3 = *(const float4*)&egb[(size_t)(blk + 4) * 256];
                float part = gv4.x * ftanh_(qg4.x + c.x) + gv4.y * ftanh_(qg4.y + c.y)
                           + gv4.z * ftanh_(qg4.z + c.z) + gv4.w * ftanh_(qg4.w + c.w);
                part += __shfl_xor(part, 1);
                part += __shfl_xor(part, 2);
                part += __shfl_xor(part, 4);
                part += __shfl_xor(part, 8);
                part += __shfl_xor(part, 16);     // 32-lane group sum -> u[n]
                const int n = 2 * blk + nh;
                float w = ((mk >> n) & 1ull) ? 0.f : __expf(part);  // |u|<=sum|gv|~5: exp safe
                l += w;
                acc.x += w * c.x; acc.y += w * c.y; acc.z += w * c.z; acc.w += w * c.w;
            }
            // combine the two row-halves
            l     += __shfl_xor(l, 32);
            acc.x += __shfl_xor(acc.x, 32);
            acc.y += __shfl_xor(acc.y, 32);
            acc.z += __shfl_xor(acc.z, 32);
            acc.w += __shfl_xor(acc.w, 32);
            float inv = 1.f / l;
            if (nh == 0) {
                float4 o = {acc.x * inv, acc.y * inv, acc.z * inv, acc.w * inv};
                *(float4*)&sGl[g][dq * 4] = o;
            }
        }

        // ---- P5: qp = gl @ pWq^T + pbq -> sQ[g] (per-wave GEMV; qg dead) ----
        if (use_t) {
            const float* wq = pqT + 2 * lane;
            float a0 = 0.f, a1 = 0.f;
#pragma unroll 8
            for (int e = 0; e < 128; e += 4) {
                float4 h4 = *(const float4*)&sGl[g][e];         // wave-uniform broadcast
                float2 w0 = *(const float2*)&wq[(size_t)(e + 0) * 128];
                float2 w1 = *(const float2*)&wq[(size_t)(e + 1) * 128];
                float2 w2 = *(const float2*)&wq[(size_t)(e + 2) * 128];
                float2 w3 = *(const float2*)&wq[(size_t)(e + 3) * 128];
                a0 += w0.x * h4.x + w1.x * h4.y + w2.x * h4.z + w3.x * h4.w;
                a1 += w0.y * h4.x + w1.y * h4.y + w2.y * h4.z + w3.y * h4.w;
            }
            sQ[g][2 * lane]     = a0 + sPbq[2 * lane];
            sQ[g][2 * lane + 1] = a1 + sPbq[2 * lane + 1];
        } else {
            const float* w0r = pWq + (size_t)(2 * lane) * 128;
            const float* w1r = w0r + 128;
            float a0 = 0.f, a1 = 0.f;
            for (int e = 0; e < 128; e += 4) {
                float4 h4 = *(const float4*)&sGl[g][e];
                float4 wa = *(const float4*)&w0r[e];
                float4 wb = *(const float4*)&w1r[e];
                a0 += wa.x * h4.x + wa.y * h4.y + wa.z * h4.z + wa.w * h4.w;
                a1 += wb.x * h4.x + wb.y * h4.y + wb.z * h4.z + wb.w * h4.w;
            }
            sQ[g][2 * lane]     = a0 + sPbq[2 * lane];
            sQ[g][2 * lane + 1] = a1 + sPbq[2 * lane + 1];
        }

        // ---- P6: pointer scores (same stream layout), then softmax/argmax/MLP ----
        {
            float4 qp4 = *(const float4*)&sQ[g][dq * 4];
            float4 pv4 = *(const float4*)&sPv[dq * 4];
            const float* epb = e_p + (size_t)b * (N_ * D_) + nh * D_ + dq * 4;
            float4 p0 = *(const float4*)&epb[0 * 256];
            float4 p1 = *(const float4*)&epb[1 * 256];
            float4 p2 = *(const float4*)&epb[2 * 256];
            float4 p3 = *(const float4*)&epb[3 * 256];
#pragma unroll
            for (int blk = 0; blk < 25; ++blk) {
                float4 c = p0; p0 = p1; p1 = p2; p2 = p3;
                if (blk + 4 < 25) p3 = *(const float4*)&epb[(size_t)(blk + 4) * 256];
                float part = pv4.x * ftanh_(qp4.x + c.x) + pv4.y * ftanh_(qp4.y + c.y)
                           + pv4.z * ftanh_(qp4.z + c.z) + pv4.w * ftanh_(qp4.w + c.w);
                part += __shfl_xor(part, 1);
                part += __shfl_xor(part, 2);
                part += __shfl_xor(part, 4);
                part += __shfl_xor(part, 8);
                part += __shfl_xor(part, 16);
                const int n = 2 * blk + nh;
                if (dq == 0) {
                    float tl = ((mk >> n) & 1ull) ? NEGV : 10.0f * ftanh_(part);
                    sLg[g][n] = tl;       // wave-local staging; regathered below
                }
            }
            const bool active = lane < N_;
            float lgv = sLg[g][lane];     // same-wave write->read: lgkmcnt handled
            float logit = active ? lgv : -__builtin_inff();
            // log-softmax over lanes
            float mx = logit;
#pragma unroll
            for (int mm = 1; mm < 64; mm <<= 1) mx = fmaxf(mx, __shfl_xor(mx, mm));
            float ex = active ? __expf(logit - mx) : 0.f;
            float s = wsum_(ex);
            float lse = mx + __logf(s);
            if (active)
                __builtin_nontemporal_store(logit - lse,
                    &outp[(size_t)b * (N_ * N_) + t * N_ + lane]);
            // argmax, first-index tie-break (matches jnp.argmax)
            float av = logit; int ai = active ? lane : (N_ - 1);
#pragma unroll
            for (int mm = 1; mm < 64; mm <<= 1) {
                float ov = __shfl_xor(av, mm);
                int   oi = __shfl_xor(ai, mm);
                bool take = (ov > av) || (ov == av && oi < ai);
                av = take ? ov : av;
                ai = take ? oi : ai;
            }
            const int idx = ai;
            // time-prediction MLP: lane = hidden unit j (TPH_ == 64)
            const float* Vl = V + ((size_t)b * N_ + lastv) * DV_;
            const float* Vi = V + ((size_t)b * N_ + idx) * DV_;
            float hacc = tpb1[lane];
#pragma unroll
            for (int k = 0; k < 8; ++k)  hacc += Vl[k] * tpW1[k * 64 + lane];
#pragma unroll
            for (int k = 0; k < 8; ++k)  hacc += Vi[k] * tpW1[(8 + k) * 64 + lane];
#pragma unroll
            for (int k = 0; k < 4; ++k)  hacc += sSF[g][k] * tpW1[(16 + k) * 64 + lane];
#pragma unroll
            for (int k = 0; k < 20; ++k) hacc += step_table[t * SE_ + k] * tpW1[(20 + k) * 64 + lane];
            hacc = fmaxf(hacc, 0.f);
            float pred = wsum_(hacc * tpW2[lane]) + tpb2[0];
            // next decoder input x2 = context_update[idx, b]  (wave-local write)
            const float* xrow = cu + ((size_t)idx * B_ + b) * D_;
            sX[g][lane]      = xrow[lane];
            sX[g][64 + lane] = xrow[64 + lane];
            if (lane == 0) {
                __builtin_nontemporal_store((float)idx,
                    &outp[(size_t)(B_ * N_) * N_ + (size_t)b * N_ + t]);
                __builtin_nontemporal_store(pred,
                    &outp[(size_t)(B_ * N_) * N_ + (size_t)(B_ * N_) + (size_t)b * N_ + t]);
                __builtin_nontemporal_store(pred,
                    &outp[(size_t)(B_ * N_) * N_ + 2 * (size_t)(B_ * N_) + (size_t)b * N_ + t]);
            }
            prev  = idx;
            lastv = idx;
        }
        __syncthreads();   // sX/sH visible to next step's P1
    }
}

extern "C" void kernel_launch(void* const* d_in, const int* in_sizes, int n_in,
                              void* d_out, int out_size, void* d_ws, size_t ws_size,
                              hipStream_t stream)
{
    const float* dec   = (const float*)d_in[0];
    const float* h0    = (const float*)d_in[1];
    const float* c0    = (const float*)d_in[2];
    const unsigned char* vmask = (const unsigned char*)d_in[3];
    const int*   sidx  = (const int*)d_in[4];
    const float* V     = (const float*)d_in[5];
    // d_in[6] b_E, d_in[7] b_E_abs, d_in[9] H_update: unused by reference
    const float* cu    = (const float*)d_in[8];
    const float* sfea  = (const float*)d_in[10];
    const float* W_ih  = (const float*)d_in[11];
    const float* W_hh  = (const float*)d_in[12];
    const float* b_ih  = (const float*)d_in[13];
    const float* b_hh  = (const float*)d_in[14];
    const float* gWq   = (const float*)d_in[15];
    const float* gbq   = (const float*)d_in[16];
    const float* gWr   = (const float*)d_in[17];
    const float* gbr   = (const float*)d_in[18];
    const float* gv    = (const float*)d_in[19];
    const float* pWq   = (const float*)d_in[20];
    const float* pbq   = (const float*)d_in[21];
    const float* pWr   = (const float*)d_in[22];
    const float* pbr   = (const float*)d_in[23];
    const float* pv    = (const float*)d_in[24];
    const float* stept = (const float*)d_in[25];
    const float* tpW1  = (const float*)d_in[26];
    const float* tpb1  = (const float*)d_in[27];
    const float* tpW2  = (const float*)d_in[28];
    const float* tpb2  = (const float*)d_in[29];

    const size_t EG = (size_t)B_ * N_ * D_;          // 26,214,400 floats
    float* e_g = (float*)d_ws;
    float* e_p = e_g + EG;

    // Transposed weights appended after e_p (needs +640 KB of ws)
    float* wtI = e_p + EG;
    float* wtH = wtI + 512 * 128;
    float* gqT = wtH + 512 * 128;
    float* pqT = gqT + 128 * 128;
    const size_t need = (2 * EG + 2 * (512 * 128) + 2 * (128 * 128)) * sizeof(float);
    const int use_t = (ws_size >= need) ? 1 : 0;

    // Precompute fixed attention keys (step-invariant)
    proj_kernel<<<dim3(1024), 256, 0, stream>>>(gWr, gbr, cu, e_g);
    proj_kernel<<<dim3(1024), 256, 0, stream>>>(pWr, pbr, cu, e_p);
    if (use_t) {
        transpose_kernel<<<dim3(256), 256, 0, stream>>>(W_ih, wtI, 512, 128);
        transpose_kernel<<<dim3(256), 256, 0, stream>>>(W_hh, wtH, 512, 128);
        transpose_kernel<<<dim3(64),  256, 0, stream>>>(gWq,  gqT, 128, 128);
        transpose_kernel<<<dim3(64),  256, 0, stream>>>(pWq,  pqT, 128, 128);
    }
    // Persistent 50-step decode: 256 blocks x 1024 threads, 16 batch rows/block
    decode_kernel<<<dim3(NBLK), 1024, 0, stream>>>(
        dec, h0, c0, vmask, sidx, V, cu, sfea,
        W_ih, W_hh, b_ih, b_hh,
        gWq, gbq, gv, pWq, pbq, pv,
        stept, tpW1, tpb1, tpW2, tpb2,
        e_g, e_p, wtI, wtH, gqT, pqT, use_t, (float*)d_out);
}